// Round 1
// baseline (657.035 us; speedup 1.0000x reference)
//
#include <hip/hip_runtime.h>

typedef unsigned int uint;
typedef unsigned short ushort;

using s16x8 = __attribute__((ext_vector_type(8))) short;
using f32x4 = __attribute__((ext_vector_type(4))) float;

#define NPIX 65536   // 16 * 64 * 64 pixels
#define LDF 544      // feat row stride: 512 (h1) + 25 (gs) + 7 pad

// ---------- helpers ----------
__device__ __forceinline__ ushort f2bf(float f) {
    uint u = __float_as_uint(f);
    u += 0x7fffu + ((u >> 16) & 1u);   // RNE
    return (ushort)(u >> 16);
}
__device__ __forceinline__ float bf2f(uint h) { return __uint_as_float(h << 16); }

__device__ __forceinline__ void async16(const void* g, void* l) {
    __builtin_amdgcn_global_load_lds(
        (const __attribute__((address_space(1))) void*)g,
        (__attribute__((address_space(3))) void*)l, 16, 0, 0);
}

// ---------- x (b,c,h,w) fp32 -> xT [n][c] bf16 ----------
__global__ __launch_bounds__(256) void txpose(const float* __restrict__ x, ushort* __restrict__ xT) {
    __shared__ float tile[32][33];
    int t = threadIdx.x, col = t & 31, rq = t >> 5;
    size_t srcBase = ((size_t)blockIdx.z * 1024 + blockIdx.y * 32) * 4096 + blockIdx.x * 32;
#pragma unroll
    for (int r = 0; r < 4; ++r) {
        int row = rq + r * 8;                       // c_local
        tile[row][col] = x[srcBase + (size_t)row * 4096 + col];
    }
    __syncthreads();
    size_t dstBase = ((size_t)blockIdx.z * 4096 + blockIdx.x * 32) * 1024 + blockIdx.y * 32;
#pragma unroll
    for (int r = 0; r < 4; ++r) {
        int row = rq + r * 8;                       // s_local
        xT[dstBase + (size_t)row * 1024 + col] = f2bf(tile[col][row]);
    }
}

// ---------- weight fp32 -> bf16 with column pad ----------
__global__ void convw(const float* __restrict__ w, ushort* __restrict__ o, int rows, int ic, int oc) {
    int i = blockIdx.x * 256 + threadIdx.x;
    if (i >= rows * oc) return;
    int r = i / oc, c = i - r * oc;
    o[i] = (c < ic) ? f2bf(w[(size_t)r * ic + c]) : (ushort)0;
}

// ---------- 128x128 bf16 MFMA GEMM: C[m][o] = sum_k A[m][k] * Bw[o][k] ----------
// m97 structure: BK=32, 4 waves (2x2), global_load_lds width-16 staging.
__global__ __launch_bounds__(256) void gemm_bt(const ushort* __restrict__ A, const ushort* __restrict__ Bw,
                                               ushort* __restrict__ C, int K, int ldC) {
    __shared__ ushort Al[128 * 32];
    __shared__ ushort Bl[128 * 32];
    int t = threadIdx.x, wv = t >> 6, lane = t & 63;
    int wr = wv >> 1, wc = wv & 1;
    int row0 = blockIdx.y * 128, col0 = blockIdx.x * 128;
    int g = lane >> 4, rr = lane & 15;

    const f32x4 fzero = {0.f, 0.f, 0.f, 0.f};
    f32x4 acc[4][4];
#pragma unroll
    for (int i = 0; i < 4; ++i)
#pragma unroll
        for (int j = 0; j < 4; ++j) acc[i][j] = fzero;

    for (int k0 = 0; k0 < K; k0 += 32) {
#pragma unroll
        for (int q = 0; q < 2; ++q) {
            int ch = q * 4 + wv;                 // 8 chunks of 1KB per tile
            int e = ch * 512 + lane * 8;         // element index in [128][32] tile
            int nl = e >> 5, cof = e & 31;
            async16(A + (size_t)(row0 + nl) * K + k0 + cof, &Al[ch * 512]);
            async16(Bw + (size_t)(col0 + nl) * K + k0 + cof, &Bl[ch * 512]);
        }
        __syncthreads();                          // drains vmcnt(0) -> LDS valid
        s16x8 av[4], bv[4];
#pragma unroll
        for (int i = 0; i < 4; ++i) {
            av[i] = *(const s16x8*)&Al[(wr * 64 + i * 16 + rr) * 32 + g * 8];
            bv[i] = *(const s16x8*)&Bl[(wc * 64 + i * 16 + rr) * 32 + g * 8];
        }
#pragma unroll
        for (int mi = 0; mi < 4; ++mi)
#pragma unroll
            for (int ni = 0; ni < 4; ++ni)
                acc[mi][ni] = __builtin_amdgcn_mfma_f32_16x16x32_bf16(av[mi], bv[ni], acc[mi][ni], 0, 0, 0);
        __syncthreads();
    }
    // C/D layout (verified): col = lane&15, row = (lane>>4)*4 + reg
#pragma unroll
    for (int mi = 0; mi < 4; ++mi)
#pragma unroll
        for (int ni = 0; ni < 4; ++ni)
#pragma unroll
            for (int e2 = 0; e2 < 4; ++e2) {
                int row = row0 + wr * 64 + mi * 16 + g * 4 + e2;
                int col = col0 + wc * 64 + ni * 16 + rr;
                C[(size_t)row * ldC + col] = f2bf(acc[mi][ni][e2]);
            }
}

// ---------- per-channel sum / sumsq over 65536 rows ----------
__global__ __launch_bounds__(256) void stats_k(const ushort* __restrict__ Y, int ld, float* __restrict__ st) {
    int t = threadIdx.x, c = t * 2;
    int r0 = blockIdx.x * 128;
    float s0 = 0, s1 = 0, q0 = 0, q1 = 0;
    for (int r = 0; r < 128; ++r) {
        uint v = *(const uint*)(Y + (size_t)(r0 + r) * ld + c);
        float a = bf2f(v & 0xffffu), b = bf2f(v >> 16);
        s0 += a; s1 += b; q0 += a * a; q1 += b * b;
    }
    atomicAdd(st + c, s0);       atomicAdd(st + c + 1, s1);
    atomicAdd(st + 512 + c, q0); atomicAdd(st + 512 + c + 1, q1);
}

// ---------- in-place BN (+optional ReLU) on [n][512] bf16 (row stride ld) ----------
__global__ __launch_bounds__(256) void apply_bn(ushort* __restrict__ Y, int ld, const float* __restrict__ st,
                                                const float* __restrict__ gamma, const float* __restrict__ beta,
                                                int relu) {
    __shared__ float sc[512], sh[512];
    int t = threadIdx.x;
    for (int c = t; c < 512; c += 256) {
        float mean = st[c] * (1.f / 65536.f);
        float var = st[512 + c] * (1.f / 65536.f) - mean * mean;
        float rs = rsqrtf(var + 1e-5f);
        float s = rs * gamma[c];
        sc[c] = s; sh[c] = beta[c] - mean * s;
    }
    __syncthreads();
    float s0 = sc[t * 2], s1 = sc[t * 2 + 1], h0 = sh[t * 2], h1v = sh[t * 2 + 1];
    for (int row = blockIdx.x; row < NPIX; row += gridDim.x) {
        uint* p = (uint*)(Y + (size_t)row * ld + t * 2);
        uint v = *p;
        float a = bf2f(v & 0xffffu) * s0 + h0;
        float b = bf2f(v >> 16) * s1 + h1v;
        if (relu) { a = fmaxf(a, 0.f); b = fmaxf(b, 0.f); }
        *p = (uint)f2bf(a) | ((uint)f2bf(b) << 16);
    }
}

// ---------- 5x5 local self-correlation + L2 norm; wave per pixel ----------
__global__ __launch_bounds__(256) void selfcorr(ushort* __restrict__ feat) {
    __shared__ float pd[4][32];
    int t = threadIdx.x, wv = t >> 6, lane = t & 63;
    int n = blockIdx.x * 4 + wv;
    int b = n >> 12, s = n & 4095, hh = s >> 6, wwp = s & 63;

    uint4 cv = *(const uint4*)(feat + (size_t)n * LDF + lane * 8);
    float cf[8];
    cf[0] = bf2f(cv.x & 0xffffu); cf[1] = bf2f(cv.x >> 16);
    cf[2] = bf2f(cv.y & 0xffffu); cf[3] = bf2f(cv.y >> 16);
    cf[4] = bf2f(cv.z & 0xffffu); cf[5] = bf2f(cv.z >> 16);
    cf[6] = bf2f(cv.w & 0xffffu); cf[7] = bf2f(cv.w >> 16);

    float nsq = 0.f;
#pragma unroll
    for (int p = 0; p < 25; ++p) {
        int dy = p / 5 - 2, dx = p % 5 - 2;
        int yy = hh + dy, xx = wwp + dx;
        float dot = 0.f;
        if (yy >= 0 && yy < 64 && xx >= 0 && xx < 64) {   // wave-uniform branch
            int n2 = (b << 12) + (yy << 6) + xx;
            uint4 nv = *(const uint4*)(feat + (size_t)n2 * LDF + lane * 8);
            dot = cf[0] * bf2f(nv.x & 0xffffu) + cf[1] * bf2f(nv.x >> 16)
                + cf[2] * bf2f(nv.y & 0xffffu) + cf[3] * bf2f(nv.y >> 16)
                + cf[4] * bf2f(nv.z & 0xffffu) + cf[5] * bf2f(nv.z >> 16)
                + cf[6] * bf2f(nv.w & 0xffffu) + cf[7] * bf2f(nv.w >> 16);
#pragma unroll
            for (int off = 1; off < 64; off <<= 1) dot += __shfl_xor(dot, off);
        }
        nsq += dot * dot;
        if (lane == 0) pd[wv][p] = dot;
    }
    __syncthreads();
    float inv = rsqrtf(nsq + 1e-6f);   // ref: f / sqrt(sum + 1e-6)
    if (lane < 32) {
        float v = (lane < 25) ? pd[wv][lane] * inv : 0.f;
        feat[(size_t)n * LDF + 512 + lane] = f2bf(v);
    }
}

// ---------- final: BN (no ReLU) + transpose [n][o] -> (b,o,h,w) fp32 ----------
__global__ __launch_bounds__(256) void finalk(const ushort* __restrict__ y3, const float* __restrict__ st,
                                              const float* __restrict__ gamma, const float* __restrict__ beta,
                                              float* __restrict__ out) {
    __shared__ float tile[32][33];
    int t = threadIdx.x, col = t & 31, rq = t >> 5;
    int n0 = blockIdx.x * 32, o0 = blockIdx.y * 32;
#pragma unroll
    for (int r = 0; r < 4; ++r) {
        int row = rq + r * 8;                        // n_local
        tile[row][col] = bf2f((uint)y3[(size_t)(n0 + row) * 512 + o0 + col]);
    }
    __syncthreads();
    int b = n0 >> 12, s0 = n0 & 4095;
#pragma unroll
    for (int r = 0; r < 4; ++r) {
        int orow = rq + r * 8;                       // o_local
        int o = o0 + orow;
        float mean = st[o] * (1.f / 65536.f);
        float var = st[512 + o] * (1.f / 65536.f) - mean * mean;
        float rs = rsqrtf(var + 1e-5f);
        float sc = rs * gamma[o];
        float sh = beta[o] - mean * sc;
        out[((size_t)b * 512 + o) * 4096 + s0 + col] = tile[col][orow] * sc + sh;
    }
}

// ---------- launch ----------
extern "C" void kernel_launch(void* const* d_in, const int* in_sizes, int n_in,
                              void* d_out, int out_size, void* d_ws, size_t ws_size,
                              hipStream_t stream) {
    (void)in_sizes; (void)n_in; (void)out_size; (void)ws_size;
    const float* x     = (const float*)d_in[0];
    const float* w_in  = (const float*)d_in[1];
    const float* g1    = (const float*)d_in[2];
    const float* b1    = (const float*)d_in[3];
    const float* w_emb = (const float*)d_in[4];
    const float* g2    = (const float*)d_in[5];
    const float* b2    = (const float*)d_in[6];
    const float* w_out = (const float*)d_in[7];
    const float* g3    = (const float*)d_in[8];
    const float* b3    = (const float*)d_in[9];
    float* out = (float*)d_out;

    char* ws = (char*)d_ws;
    // layout (bytes):
    //   [0, 128Mi)            xT bf16 [65536][1024]; after GEMM1 reused:
    //                         y3 = [0,64Mi), h2 = [64Mi,128Mi)
    //   [128Mi, 128Mi+68Mi)   feat bf16 [65536][544]
    //   then bf16 weights + stats
    ushort* xT   = (ushort*)ws;
    ushort* y3   = (ushort*)ws;
    ushort* h2   = (ushort*)(ws + 67108864);
    ushort* feat = (ushort*)(ws + 134217728);
    char* wb     = ws + 134217728 + 71303168;
    ushort* wbin  = (ushort*)wb;                            // 512*1024*2
    ushort* wbemb = (ushort*)(wb + 1048576);                // 512*544*2
    ushort* wbout = (ushort*)(wb + 1048576 + 557056);       // 512*512*2
    float*  stats = (float*)(wb + 1048576 + 557056 + 524288); // 3 * 1024 f32

    hipMemsetAsync(stats, 0, 3 * 1024 * sizeof(float), stream);

    convw<<<(512 * 1024 + 255) / 256, 256, 0, stream>>>(w_in, wbin, 512, 1024, 1024);
    convw<<<(512 * 544 + 255) / 256, 256, 0, stream>>>(w_emb, wbemb, 512, 537, 544);
    convw<<<(512 * 512 + 255) / 256, 256, 0, stream>>>(w_out, wbout, 512, 512, 512);

    txpose<<<dim3(128, 32, 16), 256, 0, stream>>>(x, xT);

    // stage 1: conv1x1_in -> BN -> ReLU  (writes into feat cols 0..511)
    gemm_bt<<<dim3(4, 512), 256, 0, stream>>>(xT, wbin, feat, 1024, LDF);
    stats_k<<<512, 256, 0, stream>>>(feat, LDF, stats);
    apply_bn<<<2048, 256, 0, stream>>>(feat, LDF, stats, g1, b1, 1);

    // spatial descriptor -> feat cols 512..543 (25 real + 7 zeros)
    selfcorr<<<16384, 256, 0, stream>>>(feat);

    // stage 2: embeddingFea
    gemm_bt<<<dim3(4, 512), 256, 0, stream>>>(feat, wbemb, h2, 544, 512);
    stats_k<<<512, 256, 0, stream>>>(h2, 512, stats + 1024);
    apply_bn<<<2048, 256, 0, stream>>>(h2, 512, stats + 1024, g2, b2, 1);

    // stage 3: conv1x1_out -> BN (no ReLU), then transpose to NCHW
    gemm_bt<<<dim3(4, 512), 256, 0, stream>>>(h2, wbout, y3, 512, 512);
    stats_k<<<512, 256, 0, stream>>>(y3, 512, stats + 2048);
    finalk<<<dim3(2048, 16), 256, 0, stream>>>(y3, stats + 2048, g3, b3, out);
}

// Round 2
// 527.118 us; speedup vs baseline: 1.2465x; 1.2465x over previous
//
#include <hip/hip_runtime.h>

typedef unsigned int uint;
typedef unsigned short ushort;

using s16x8 = __attribute__((ext_vector_type(8))) short;
using f32x4 = __attribute__((ext_vector_type(4))) float;

#define NPIX 65536   // 16 * 64 * 64 pixels
#define LDF 544      // feat row stride: 512 (h1) + 25 (gs) + 7 pad

// ---------- helpers ----------
__device__ __forceinline__ ushort f2bf(float f) {
    uint u = __float_as_uint(f);
    u += 0x7fffu + ((u >> 16) & 1u);   // RNE
    return (ushort)(u >> 16);
}
__device__ __forceinline__ float bf2f(uint h) { return __uint_as_float(h << 16); }

__device__ __forceinline__ void async16(const void* g, void* l) {
    __builtin_amdgcn_global_load_lds(
        (const __attribute__((address_space(1))) void*)g,
        (__attribute__((address_space(3))) void*)l, 16, 0, 0);
}

// ---------- x (b,c,h,w) fp32 -> xT [n][c] bf16 ----------
__global__ __launch_bounds__(256) void txpose(const float* __restrict__ x, ushort* __restrict__ xT) {
    __shared__ float tile[32][33];
    int t = threadIdx.x, col = t & 31, rq = t >> 5;
    size_t srcBase = ((size_t)blockIdx.z * 1024 + blockIdx.y * 32) * 4096 + blockIdx.x * 32;
#pragma unroll
    for (int r = 0; r < 4; ++r) {
        int row = rq + r * 8;                       // c_local
        tile[row][col] = x[srcBase + (size_t)row * 4096 + col];
    }
    __syncthreads();
    size_t dstBase = ((size_t)blockIdx.z * 4096 + blockIdx.x * 32) * 1024 + blockIdx.y * 32;
#pragma unroll
    for (int r = 0; r < 4; ++r) {
        int row = rq + r * 8;                       // s_local
        xT[dstBase + (size_t)row * 1024 + col] = f2bf(tile[col][row]);
    }
}

// ---------- all three weights fp32 -> bf16 (w_emb column-padded 537->544) ----------
__global__ __launch_bounds__(256) void convw_all(const float* __restrict__ w_in, const float* __restrict__ w_emb,
                                                 const float* __restrict__ w_out,
                                                 ushort* __restrict__ o1, ushort* __restrict__ o2, ushort* __restrict__ o3) {
    int i = blockIdx.x * 256 + threadIdx.x;
    if (i < 524288) {                                  // 512x1024
        o1[i] = f2bf(w_in[i]);
    } else if (i < 524288 + 278528) {                  // 512x544 padded
        int j = i - 524288;
        int r = j / 544, c = j - r * 544;
        o2[j] = (c < 537) ? f2bf(w_emb[(size_t)r * 537 + c]) : (ushort)0;
    } else if (i < 524288 + 278528 + 262144) {         // 512x512
        int j = i - 802816;
        o3[j] = f2bf(w_out[j]);
    }
}

// ---------- 128x128 bf16 MFMA GEMM + fused per-channel sum/sumsq ----------
// C[m][o] = sum_k A[m][k]*Bw[o][k]; st[col] += colsum, st[512+col] += colsumsq.
// XCD swizzle: the 4 col-tiles sharing an A row-panel land on the SAME XCD.
__global__ __launch_bounds__(256) void gemm_bt_stats(const ushort* __restrict__ A, const ushort* __restrict__ Bw,
                                                     ushort* __restrict__ C, int K, int ldC,
                                                     float* __restrict__ st) {
    __shared__ ushort Al[128 * 32];
    __shared__ ushort Bl[128 * 32];
    int hbid = blockIdx.x;                  // 2048 blocks
    int xcd = hbid & 7, slot = hbid >> 3;   // hw round-robins id%8 across XCDs
    int by = (xcd << 6) + (slot >> 2);      // row-panel: 64 panels per XCD
    int bx = slot & 3;                      // 4 col tiles of one panel -> same XCD
    int row0 = by * 128, col0 = bx * 128;

    int t = threadIdx.x, wv = t >> 6, lane = t & 63;
    int wr = wv >> 1, wc = wv & 1;
    int g = lane >> 4, rr = lane & 15;

    const f32x4 fzero = {0.f, 0.f, 0.f, 0.f};
    f32x4 acc[4][4];
#pragma unroll
    for (int i = 0; i < 4; ++i)
#pragma unroll
        for (int j = 0; j < 4; ++j) acc[i][j] = fzero;

    for (int k0 = 0; k0 < K; k0 += 32) {
#pragma unroll
        for (int q = 0; q < 2; ++q) {
            int ch = q * 4 + wv;
            int e = ch * 512 + lane * 8;
            int nl = e >> 5, cof = e & 31;
            async16(A + (size_t)(row0 + nl) * K + k0 + cof, &Al[ch * 512]);
            async16(Bw + (size_t)(col0 + nl) * K + k0 + cof, &Bl[ch * 512]);
        }
        __syncthreads();
        s16x8 av[4], bv[4];
#pragma unroll
        for (int i = 0; i < 4; ++i) {
            av[i] = *(const s16x8*)&Al[(wr * 64 + i * 16 + rr) * 32 + g * 8];
            bv[i] = *(const s16x8*)&Bl[(wc * 64 + i * 16 + rr) * 32 + g * 8];
        }
#pragma unroll
        for (int mi = 0; mi < 4; ++mi)
#pragma unroll
            for (int ni = 0; ni < 4; ++ni)
                acc[mi][ni] = __builtin_amdgcn_mfma_f32_16x16x32_bf16(av[mi], bv[ni], acc[mi][ni], 0, 0, 0);
        __syncthreads();
    }
    // C/D layout: col = lane&15, row = (lane>>4)*4 + reg
#pragma unroll
    for (int mi = 0; mi < 4; ++mi)
#pragma unroll
        for (int ni = 0; ni < 4; ++ni)
#pragma unroll
            for (int e2 = 0; e2 < 4; ++e2) {
                int row = row0 + wr * 64 + mi * 16 + g * 4 + e2;
                int col = col0 + wc * 64 + ni * 16 + rr;
                C[(size_t)row * ldC + col] = f2bf(acc[mi][ni][e2]);
            }
    // fused BN stats: per-column sum / sumsq from fp32 acc
#pragma unroll
    for (int ni = 0; ni < 4; ++ni) {
        float s = 0.f, q = 0.f;
#pragma unroll
        for (int mi = 0; mi < 4; ++mi)
#pragma unroll
            for (int e2 = 0; e2 < 4; ++e2) {
                float v = acc[mi][ni][e2];
                s += v; q += v * v;
            }
        s += __shfl_xor(s, 16); s += __shfl_xor(s, 32);
        q += __shfl_xor(q, 16); q += __shfl_xor(q, 32);
        if (lane < 16) {
            int col = col0 + wc * 64 + ni * 16 + rr;
            atomicAdd(st + col, s);
            atomicAdd(st + 512 + col, q);
        }
    }
}

// ---------- LDS-tiled selfcorr: BN1+ReLU fused into staging, 4x4 patch + halo ----------
// Reads raw y1 [n][512], writes normalized h1 into feat cols 0..511 and gs into 512..536.
#define RSTEP(S, HALF)                                                            \
    _Pragma("unroll") for (int i_ = 0; i_ < HALF; ++i_) {                         \
        float lo_ = p[i_], hi_ = p[HALF + i_];                                    \
        float send_ = (lane & S) ? lo_ : hi_;                                     \
        float keep_ = (lane & S) ? hi_ : lo_;                                     \
        p[i_] = keep_ + __shfl_xor(send_, S);                                     \
    }

__global__ __launch_bounds__(256) void selfcorr2(const ushort* __restrict__ y1, ushort* __restrict__ feat,
                                                 const float* __restrict__ st,
                                                 const float* __restrict__ gamma, const float* __restrict__ beta) {
    __shared__ ushort hl[64 * 512];        // 8x8 halo rows x 512 ch, post-BN bf16
    int h = blockIdx.x;                    // 4096 blocks; XCD swizzle for halo L2 reuse
    int xcd = h & 7, slot = h >> 3;
    int flat = xcd * 512 + slot;
    int bz = flat >> 8, rem = flat & 255;
    int y0 = (rem >> 4) * 4, x0 = (rem & 15) * 4;

    int t = threadIdx.x, wv = t >> 6, lane = t & 63;

    // per-thread BN coeffs for channels lane*8 .. +8 (same channels for all its chunks)
    float scv[8], shv[8];
#pragma unroll
    for (int i = 0; i < 8; ++i) {
        int c = lane * 8 + i;
        float mean = st[c] * (1.f / 65536.f);
        float var = st[512 + c] * (1.f / 65536.f) - mean * mean;
        float rs = rsqrtf(var + 1e-5f);
        float s = rs * gamma[c];
        scv[i] = s; shv[i] = beta[c] - mean * s;
    }

    // stage halo with BN+ReLU (OOB rows stay exactly zero, matching ref zero-pad)
#pragma unroll
    for (int i = 0; i < 16; ++i) {
        int rid = i * 4 + wv;              // wave reads one contiguous 1KB row
        int ry = rid >> 3, rx = rid & 7;
        int y = y0 - 2 + ry, x = x0 - 2 + rx;
        uint4 w4 = {0u, 0u, 0u, 0u};
        if (y >= 0 && y < 64 && x >= 0 && x < 64) {
            int n2 = (bz << 12) + (y << 6) + x;
            uint4 v = *(const uint4*)(y1 + (size_t)n2 * 512 + lane * 8);
            float a0 = fmaxf(bf2f(v.x & 0xffffu) * scv[0] + shv[0], 0.f);
            float a1 = fmaxf(bf2f(v.x >> 16)     * scv[1] + shv[1], 0.f);
            float a2 = fmaxf(bf2f(v.y & 0xffffu) * scv[2] + shv[2], 0.f);
            float a3 = fmaxf(bf2f(v.y >> 16)     * scv[3] + shv[3], 0.f);
            float a4 = fmaxf(bf2f(v.z & 0xffffu) * scv[4] + shv[4], 0.f);
            float a5 = fmaxf(bf2f(v.z >> 16)     * scv[5] + shv[5], 0.f);
            float a6 = fmaxf(bf2f(v.w & 0xffffu) * scv[6] + shv[6], 0.f);
            float a7 = fmaxf(bf2f(v.w >> 16)     * scv[7] + shv[7], 0.f);
            w4.x = (uint)f2bf(a0) | ((uint)f2bf(a1) << 16);
            w4.y = (uint)f2bf(a2) | ((uint)f2bf(a3) << 16);
            w4.z = (uint)f2bf(a4) | ((uint)f2bf(a5) << 16);
            w4.w = (uint)f2bf(a6) | ((uint)f2bf(a7) << 16);
        }
        *(uint4*)&hl[rid * 512 + lane * 8] = w4;
    }
    __syncthreads();

    // write back normalized interior h1 (each pixel owned by exactly one block)
#pragma unroll
    for (int i = 0; i < 4; ++i) {
        int pid = i * 4 + wv;
        int py = pid >> 2, px = pid & 3;
        int rid = (py + 2) * 8 + (px + 2);
        uint4 v = *(const uint4*)&hl[rid * 512 + lane * 8];
        int n2 = (bz << 12) + ((y0 + py) << 6) + (x0 + px);
        *(uint4*)(feat + (size_t)n2 * LDF + lane * 8) = v;
    }

    // compute: wave wv owns pixels (py=wv, px=0..3)
    for (int j = 0; j < 4; ++j) {
        int crid = (wv + 2) * 8 + (j + 2);
        uint4 cv = *(const uint4*)&hl[crid * 512 + lane * 8];
        float cf[8];
        cf[0] = bf2f(cv.x & 0xffffu); cf[1] = bf2f(cv.x >> 16);
        cf[2] = bf2f(cv.y & 0xffffu); cf[3] = bf2f(cv.y >> 16);
        cf[4] = bf2f(cv.z & 0xffffu); cf[5] = bf2f(cv.z >> 16);
        cf[6] = bf2f(cv.w & 0xffffu); cf[7] = bf2f(cv.w >> 16);

        float p[32];
#pragma unroll
        for (int i = 0; i < 32; ++i) p[i] = 0.f;
#pragma unroll
        for (int tap = 0; tap < 25; ++tap) {
            int dy = tap / 5 - 2, dx = tap % 5 - 2;
            int rid = (wv + 2 + dy) * 8 + (j + 2 + dx);
            uint4 nv = *(const uint4*)&hl[rid * 512 + lane * 8];
            p[tap] = cf[0] * bf2f(nv.x & 0xffffu) + cf[1] * bf2f(nv.x >> 16)
                   + cf[2] * bf2f(nv.y & 0xffffu) + cf[3] * bf2f(nv.y >> 16)
                   + cf[4] * bf2f(nv.z & 0xffffu) + cf[5] * bf2f(nv.z >> 16)
                   + cf[6] * bf2f(nv.w & 0xffffu) + cf[7] * bf2f(nv.w >> 16);
        }
        // reduce-scatter butterfly: lane ends holding tap bitrev5(lane) fully reduced
        RSTEP(1, 16) RSTEP(2, 8) RSTEP(4, 4) RSTEP(8, 2) RSTEP(16, 1)
        float d = p[0] + __shfl_xor(p[0], 32);
        float v2 = d * d;
#pragma unroll
        for (int m = 1; m < 64; m <<= 1) v2 += __shfl_xor(v2, m);   // = 2 * sum_t dot^2
        float inv = rsqrtf(0.5f * v2 + 1e-6f);
        int tt = ((lane & 1) << 4) | ((lane & 2) << 2) | (lane & 4) | ((lane & 8) >> 2) | ((lane & 16) >> 4);
        if (lane < 32 && tt < 25) {
            int n2 = (bz << 12) + ((y0 + wv) << 6) + (x0 + j);
            feat[(size_t)n2 * LDF + 512 + tt] = f2bf(d * inv);
        }
    }
}

// ---------- in-place BN+ReLU on [n][512] bf16 ----------
__global__ __launch_bounds__(256) void apply_bn(ushort* __restrict__ Y, int ld, const float* __restrict__ st,
                                                const float* __restrict__ gamma, const float* __restrict__ beta,
                                                int relu) {
    __shared__ float sc[512], sh[512];
    int t = threadIdx.x;
    for (int c = t; c < 512; c += 256) {
        float mean = st[c] * (1.f / 65536.f);
        float var = st[512 + c] * (1.f / 65536.f) - mean * mean;
        float rs = rsqrtf(var + 1e-5f);
        float s = rs * gamma[c];
        sc[c] = s; sh[c] = beta[c] - mean * s;
    }
    __syncthreads();
    float s0 = sc[t * 2], s1 = sc[t * 2 + 1], h0 = sh[t * 2], h1v = sh[t * 2 + 1];
    for (int row = blockIdx.x; row < NPIX; row += gridDim.x) {
        uint* p = (uint*)(Y + (size_t)row * ld + t * 2);
        uint v = *p;
        float a = bf2f(v & 0xffffu) * s0 + h0;
        float b = bf2f(v >> 16) * s1 + h1v;
        if (relu) { a = fmaxf(a, 0.f); b = fmaxf(b, 0.f); }
        *p = (uint)f2bf(a) | ((uint)f2bf(b) << 16);
    }
}

// ---------- final: BN (no ReLU) + transpose [n][o] -> (b,o,h,w) fp32 ----------
__global__ __launch_bounds__(256) void finalk(const ushort* __restrict__ y3, const float* __restrict__ st,
                                              const float* __restrict__ gamma, const float* __restrict__ beta,
                                              float* __restrict__ out) {
    __shared__ float tile[32][33];
    int t = threadIdx.x, col = t & 31, rq = t >> 5;
    int n0 = blockIdx.x * 32, o0 = blockIdx.y * 32;
#pragma unroll
    for (int r = 0; r < 4; ++r) {
        int row = rq + r * 8;                        // n_local
        tile[row][col] = bf2f((uint)y3[(size_t)(n0 + row) * 512 + o0 + col]);
    }
    __syncthreads();
    int b = n0 >> 12, s0 = n0 & 4095;
#pragma unroll
    for (int r = 0; r < 4; ++r) {
        int orow = rq + r * 8;                       // o_local
        int o = o0 + orow;
        float mean = st[o] * (1.f / 65536.f);
        float var = st[512 + o] * (1.f / 65536.f) - mean * mean;
        float rs = rsqrtf(var + 1e-5f);
        float sc = rs * gamma[o];
        float sh = beta[o] - mean * sc;
        out[((size_t)b * 512 + o) * 4096 + s0 + col] = tile[col][orow] * sc + sh;
    }
}

// ---------- launch ----------
extern "C" void kernel_launch(void* const* d_in, const int* in_sizes, int n_in,
                              void* d_out, int out_size, void* d_ws, size_t ws_size,
                              hipStream_t stream) {
    (void)in_sizes; (void)n_in; (void)out_size; (void)ws_size;
    const float* x     = (const float*)d_in[0];
    const float* w_in  = (const float*)d_in[1];
    const float* g1    = (const float*)d_in[2];
    const float* b1    = (const float*)d_in[3];
    const float* w_emb = (const float*)d_in[4];
    const float* g2    = (const float*)d_in[5];
    const float* b2    = (const float*)d_in[6];
    const float* w_out = (const float*)d_in[7];
    const float* g3    = (const float*)d_in[8];
    const float* b3    = (const float*)d_in[9];
    float* out = (float*)d_out;

    char* ws = (char*)d_ws;
    // layout (bytes):
    //   [0, 128Mi)          xT [65536][1024] bf16; reused as h2 [65536][512] after GEMM2
    //   [128Mi, 192Mi)      y1 raw [65536][512] bf16; reused as y3 after selfcorr
    //   [192Mi, 192Mi+68Mi) feat [65536][544] bf16 (h1' | gs)
    //   then bf16 weights + 3x1024 f32 stats
    ushort* xT   = (ushort*)ws;
    ushort* h2   = (ushort*)ws;
    ushort* y1   = (ushort*)(ws + 134217728);
    ushort* y3   = (ushort*)(ws + 134217728);
    ushort* feat = (ushort*)(ws + 134217728 + 67108864);
    char* wb     = ws + 134217728 + 67108864 + 71303168;
    ushort* wbin  = (ushort*)wb;                             // 512*1024*2
    ushort* wbemb = (ushort*)(wb + 1048576);                 // 512*544*2
    ushort* wbout = (ushort*)(wb + 1048576 + 557056);        // 512*512*2
    float*  stats = (float*)(wb + 1048576 + 557056 + 524288);// 3*1024 f32

    hipMemsetAsync(stats, 0, 3 * 1024 * sizeof(float), stream);
    convw_all<<<4160, 256, 0, stream>>>(w_in, w_emb, w_out, wbin, wbemb, wbout);
    txpose<<<dim3(128, 32, 16), 256, 0, stream>>>(x, xT);

    // stage 1: conv1x1_in (raw) + fused stats
    gemm_bt_stats<<<2048, 256, 0, stream>>>(xT, wbin, y1, 1024, 512, stats);
    // BN1+ReLU fused into selfcorr staging; writes h1' and gs into feat
    selfcorr2<<<4096, 256, 0, stream>>>(y1, feat, stats, g1, b1);

    // stage 2: embeddingFea + fused stats, then BN+ReLU in place
    gemm_bt_stats<<<2048, 256, 0, stream>>>(feat, wbemb, h2, 544, 512, stats + 1024);
    apply_bn<<<2048, 256, 0, stream>>>(h2, 512, stats + 1024, g2, b2, 1);

    // stage 3: conv1x1_out + fused stats, then BN + transpose to NCHW
    gemm_bt_stats<<<2048, 256, 0, stream>>>(h2, wbout, y3, 512, 512, stats + 2048);
    finalk<<<dim3(2048, 16), 256, 0, stream>>>(y3, stats + 2048, g3, b3, out);
}

// Round 3
// 501.227 us; speedup vs baseline: 1.3109x; 1.0517x over previous
//
#include <hip/hip_runtime.h>

typedef unsigned int uint;
typedef unsigned short ushort;

using s16x8 = __attribute__((ext_vector_type(8))) short;
using f32x4 = __attribute__((ext_vector_type(4))) float;

#define NPIX 65536   // 16 * 64 * 64 pixels
#define LDF 640      // feat row stride: 512 (h1) + 25 (gs) + pad to K-tile multiple (64)

// ---------- helpers ----------
__device__ __forceinline__ ushort f2bf(float f) {
    uint u = __float_as_uint(f);
    u += 0x7fffu + ((u >> 16) & 1u);   // RNE
    return (ushort)(u >> 16);
}
__device__ __forceinline__ float bf2f(uint h) { return __uint_as_float(h << 16); }

__device__ __forceinline__ void async16(const void* g, void* l) {
    __builtin_amdgcn_global_load_lds(
        (const __attribute__((address_space(1))) void*)g,
        (__attribute__((address_space(3))) void*)l, 16, 0, 0);
}

// ---------- x (b,c,h,w) fp32 -> xT [n][c] bf16 ----------
__global__ __launch_bounds__(256) void txpose(const float* __restrict__ x, ushort* __restrict__ xT) {
    __shared__ float tile[32][33];
    int t = threadIdx.x, col = t & 31, rq = t >> 5;
    size_t srcBase = ((size_t)blockIdx.z * 1024 + blockIdx.y * 32) * 4096 + blockIdx.x * 32;
#pragma unroll
    for (int r = 0; r < 4; ++r) {
        int row = rq + r * 8;                       // c_local
        tile[row][col] = x[srcBase + (size_t)row * 4096 + col];
    }
    __syncthreads();
    size_t dstBase = ((size_t)blockIdx.z * 4096 + blockIdx.x * 32) * 1024 + blockIdx.y * 32;
#pragma unroll
    for (int r = 0; r < 4; ++r) {
        int row = rq + r * 8;                       // s_local
        xT[dstBase + (size_t)row * 1024 + col] = f2bf(tile[col][row]);
    }
}

// ---------- all three weights fp32 -> bf16 (w_emb column-padded 537->640 with zeros) ----------
__global__ __launch_bounds__(256) void convw_all(const float* __restrict__ w_in, const float* __restrict__ w_emb,
                                                 const float* __restrict__ w_out,
                                                 ushort* __restrict__ o1, ushort* __restrict__ o2, ushort* __restrict__ o3) {
    int i = blockIdx.x * 256 + threadIdx.x;
    if (i < 524288) {                                  // 512x1024
        o1[i] = f2bf(w_in[i]);
    } else if (i < 524288 + 327680) {                  // 512x640 padded
        int j = i - 524288;
        int r = j / 640, c = j - r * 640;
        o2[j] = (c < 537) ? f2bf(w_emb[(size_t)r * 537 + c]) : (ushort)0;
    } else if (i < 524288 + 327680 + 262144) {         // 512x512
        int j = i - 851968;
        o3[j] = f2bf(w_out[j]);
    }
}

// ---------- 256x256 BK=64 bf16 MFMA GEMM, double-buffered, T2-swizzled, fused stats ----------
// C[m][o] = sum_k A[m][k] * Bw[o][k]   (A: [M][K] bf16, Bw: [512][K] bf16, C: [M][512] bf16)
// 8 waves (2M x 4N), per-wave C = 128x64. LDS: 2 x (A 32KB + B 32KB) = 128 KiB.
// Swizzle (involution, both sides): physical_colbyte = logical_colbyte ^ ((row&7)<<4).
// Sync: one __syncthreads per K-tile; stage loads for tile t+1 issued at top of tile t,
// drained by the barrier's implicit vmcnt(0) ~a whole tile later (latency hidden).
__global__ __launch_bounds__(512, 2) void gemm256(const ushort* __restrict__ A, const ushort* __restrict__ Bw,
                                                  ushort* __restrict__ C, int K, int ldC,
                                                  float* __restrict__ st) {
    __shared__ ushort Asm[2][256][64];
    __shared__ ushort Bsm[2][256][64];

    int id = blockIdx.x;                       // 512 blocks
    int swz = (id & 7) * 64 + (id >> 3);       // XCD x owns swz [x*64, x*64+64)
    int row0 = (swz >> 1) * 256, col0 = (swz & 1) * 256;

    int t = threadIdx.x, wv = t >> 6, lane = t & 63;
    int wr = wv >> 2, wc = wv & 3;             // wave grid 2M x 4N
    int g = lane >> 4, rr = lane & 15;

    // staging geometry: thread t stages 16B at physical LDS (row = q*64 + t>>3, colbyte = (t&7)*16)
    // source element = logical colbyte ((t&7)*16) ^ ((row&7)<<4)
    int srow = t >> 3;
    int scol = ((t & 7) * 16) ^ ((srow & 7) << 4);     // logical col byte
    const ushort* pa = A + (size_t)(row0 + srow) * K + (scol >> 1);
    const ushort* pb = Bw + (size_t)(col0 + srow) * K + (scol >> 1);

    const f32x4 fz = {0.f, 0.f, 0.f, 0.f};
    f32x4 acc[8][4];
#pragma unroll
    for (int i = 0; i < 8; ++i)
#pragma unroll
        for (int j = 0; j < 4; ++j) acc[i][j] = fz;

    int NT = K >> 6;

#define STAGE(dbuf, kt) do {                                                      \
        int k0_ = (kt) * 64;                                                      \
        _Pragma("unroll") for (int q_ = 0; q_ < 4; ++q_) {                        \
            async16(pa + (size_t)q_ * 64 * K + k0_, &Asm[dbuf][q_ * 64 + wv * 8][0]); \
            async16(pb + (size_t)q_ * 64 * K + k0_, &Bsm[dbuf][q_ * 64 + wv * 8][0]); \
        }                                                                         \
    } while (0)

    STAGE(0, 0);
    __syncthreads();

    int swzl = (rr & 7) << 4;                  // lane-constant read swizzle
    for (int kt = 0; kt < NT; ++kt) {
        int c = kt & 1;
        if (kt + 1 < NT) STAGE(c ^ 1, kt + 1);

        s16x8 bfr[4][2];
#pragma unroll
        for (int ni = 0; ni < 4; ++ni)
#pragma unroll
            for (int ks = 0; ks < 2; ++ks)
                bfr[ni][ks] = *(const s16x8*)&Bsm[c][wc * 64 + ni * 16 + rr][((ks * 64 + g * 16) ^ swzl) >> 1];

#pragma unroll
        for (int pp = 0; pp < 4; ++pp) {
            s16x8 afr[2][2];
#pragma unroll
            for (int m2 = 0; m2 < 2; ++m2)
#pragma unroll
                for (int ks = 0; ks < 2; ++ks)
                    afr[m2][ks] = *(const s16x8*)&Asm[c][wr * 128 + (pp * 2 + m2) * 16 + rr][((ks * 64 + g * 16) ^ swzl) >> 1];
            __builtin_amdgcn_s_setprio(1);
#pragma unroll
            for (int m2 = 0; m2 < 2; ++m2)
#pragma unroll
                for (int ni = 0; ni < 4; ++ni)
#pragma unroll
                    for (int ks = 0; ks < 2; ++ks)
                        acc[pp * 2 + m2][ni] = __builtin_amdgcn_mfma_f32_16x16x32_bf16(
                            afr[m2][ks], bfr[ni][ks], acc[pp * 2 + m2][ni], 0, 0, 0);
            __builtin_amdgcn_s_setprio(0);
        }
        __syncthreads();                        // drains vmcnt(0): tile kt+1 staged; buf c free for kt+2
    }
#undef STAGE

    // epilogue: C write (C/D layout: col = lane&15, row = (lane>>4)*4 + reg) + fused stats
#pragma unroll
    for (int mi = 0; mi < 8; ++mi)
#pragma unroll
        for (int ni = 0; ni < 4; ++ni)
#pragma unroll
            for (int e2 = 0; e2 < 4; ++e2) {
                int row = row0 + wr * 128 + mi * 16 + g * 4 + e2;
                int col = col0 + wc * 64 + ni * 16 + rr;
                C[(size_t)row * ldC + col] = f2bf(acc[mi][ni][e2]);
            }
#pragma unroll
    for (int ni = 0; ni < 4; ++ni) {
        float s = 0.f, q = 0.f;
#pragma unroll
        for (int mi = 0; mi < 8; ++mi)
#pragma unroll
            for (int e2 = 0; e2 < 4; ++e2) {
                float v = acc[mi][ni][e2];
                s += v; q += v * v;
            }
        s += __shfl_xor(s, 16); s += __shfl_xor(s, 32);
        q += __shfl_xor(q, 16); q += __shfl_xor(q, 32);
        if (lane < 16) {
            int col = col0 + wc * 64 + ni * 16 + rr;
            atomicAdd(st + col, s);
            atomicAdd(st + 512 + col, q);
        }
    }
}

// ---------- LDS-tiled selfcorr: BN1+ReLU fused into staging, 4x4 patch + 8x8 halo ----------
#define RSTEP(S, HALF)                                                            \
    _Pragma("unroll") for (int i_ = 0; i_ < HALF; ++i_) {                         \
        float lo_ = p[i_], hi_ = p[HALF + i_];                                    \
        float send_ = (lane & S) ? lo_ : hi_;                                     \
        float keep_ = (lane & S) ? hi_ : lo_;                                     \
        p[i_] = keep_ + __shfl_xor(send_, S);                                     \
    }

__global__ __launch_bounds__(256) void selfcorr2(const ushort* __restrict__ y1, ushort* __restrict__ feat,
                                                 const float* __restrict__ st,
                                                 const float* __restrict__ gamma, const float* __restrict__ beta) {
    __shared__ ushort hl[64 * 512];        // 8x8 halo rows x 512 ch, post-BN bf16
    int h = blockIdx.x;                    // 4096 blocks; XCD swizzle for halo L2 reuse
    int xcd = h & 7, slot = h >> 3;
    int flat = xcd * 512 + slot;
    int bz = flat >> 8, rem = flat & 255;
    int y0 = (rem >> 4) * 4, x0 = (rem & 15) * 4;

    int t = threadIdx.x, wv = t >> 6, lane = t & 63;

    float scv[8], shv[8];
#pragma unroll
    for (int i = 0; i < 8; ++i) {
        int c = lane * 8 + i;
        float mean = st[c] * (1.f / 65536.f);
        float var = st[512 + c] * (1.f / 65536.f) - mean * mean;
        float rs = rsqrtf(var + 1e-5f);
        float s = rs * gamma[c];
        scv[i] = s; shv[i] = beta[c] - mean * s;
    }

#pragma unroll
    for (int i = 0; i < 16; ++i) {
        int rid = i * 4 + wv;              // wave reads one contiguous 1KB row
        int ry = rid >> 3, rx = rid & 7;
        int y = y0 - 2 + ry, x = x0 - 2 + rx;
        uint4 w4 = {0u, 0u, 0u, 0u};
        if (y >= 0 && y < 64 && x >= 0 && x < 64) {
            int n2 = (bz << 12) + (y << 6) + x;
            uint4 v = *(const uint4*)(y1 + (size_t)n2 * 512 + lane * 8);
            float a0 = fmaxf(bf2f(v.x & 0xffffu) * scv[0] + shv[0], 0.f);
            float a1 = fmaxf(bf2f(v.x >> 16)     * scv[1] + shv[1], 0.f);
            float a2 = fmaxf(bf2f(v.y & 0xffffu) * scv[2] + shv[2], 0.f);
            float a3 = fmaxf(bf2f(v.y >> 16)     * scv[3] + shv[3], 0.f);
            float a4 = fmaxf(bf2f(v.z & 0xffffu) * scv[4] + shv[4], 0.f);
            float a5 = fmaxf(bf2f(v.z >> 16)     * scv[5] + shv[5], 0.f);
            float a6 = fmaxf(bf2f(v.w & 0xffffu) * scv[6] + shv[6], 0.f);
            float a7 = fmaxf(bf2f(v.w >> 16)     * scv[7] + shv[7], 0.f);
            w4.x = (uint)f2bf(a0) | ((uint)f2bf(a1) << 16);
            w4.y = (uint)f2bf(a2) | ((uint)f2bf(a3) << 16);
            w4.z = (uint)f2bf(a4) | ((uint)f2bf(a5) << 16);
            w4.w = (uint)f2bf(a6) | ((uint)f2bf(a7) << 16);
        }
        *(uint4*)&hl[rid * 512 + lane * 8] = w4;
    }
    __syncthreads();

    // write back normalized interior h1
#pragma unroll
    for (int i = 0; i < 4; ++i) {
        int pid = i * 4 + wv;
        int py = pid >> 2, px = pid & 3;
        int rid = (py + 2) * 8 + (px + 2);
        uint4 v = *(const uint4*)&hl[rid * 512 + lane * 8];
        int n2 = (bz << 12) + ((y0 + py) << 6) + (x0 + px);
        *(uint4*)(feat + (size_t)n2 * LDF + lane * 8) = v;
    }

    for (int j = 0; j < 4; ++j) {
        int crid = (wv + 2) * 8 + (j + 2);
        uint4 cv = *(const uint4*)&hl[crid * 512 + lane * 8];
        float cf[8];
        cf[0] = bf2f(cv.x & 0xffffu); cf[1] = bf2f(cv.x >> 16);
        cf[2] = bf2f(cv.y & 0xffffu); cf[3] = bf2f(cv.y >> 16);
        cf[4] = bf2f(cv.z & 0xffffu); cf[5] = bf2f(cv.z >> 16);
        cf[6] = bf2f(cv.w & 0xffffu); cf[7] = bf2f(cv.w >> 16);

        float p[32];
#pragma unroll
        for (int i = 0; i < 32; ++i) p[i] = 0.f;
#pragma unroll
        for (int tap = 0; tap < 25; ++tap) {
            int dy = tap / 5 - 2, dx = tap % 5 - 2;
            int rid = (wv + 2 + dy) * 8 + (j + 2 + dx);
            uint4 nv = *(const uint4*)&hl[rid * 512 + lane * 8];
            p[tap] = cf[0] * bf2f(nv.x & 0xffffu) + cf[1] * bf2f(nv.x >> 16)
                   + cf[2] * bf2f(nv.y & 0xffffu) + cf[3] * bf2f(nv.y >> 16)
                   + cf[4] * bf2f(nv.z & 0xffffu) + cf[5] * bf2f(nv.z >> 16)
                   + cf[6] * bf2f(nv.w & 0xffffu) + cf[7] * bf2f(nv.w >> 16);
        }
        RSTEP(1, 16) RSTEP(2, 8) RSTEP(4, 4) RSTEP(8, 2) RSTEP(16, 1)
        float d = p[0] + __shfl_xor(p[0], 32);
        float v2 = d * d;
#pragma unroll
        for (int m = 1; m < 64; m <<= 1) v2 += __shfl_xor(v2, m);   // = 2 * sum_t dot^2
        float inv = rsqrtf(0.5f * v2 + 1e-6f);
        int tt = ((lane & 1) << 4) | ((lane & 2) << 2) | (lane & 4) | ((lane & 8) >> 2) | ((lane & 16) >> 4);
        if (lane < 32 && tt < 25) {
            int n2 = (bz << 12) + ((y0 + wv) << 6) + (x0 + j);
            feat[(size_t)n2 * LDF + 512 + tt] = f2bf(d * inv);
        }
    }
}

// ---------- in-place BN+ReLU on [n][512] bf16 ----------
__global__ __launch_bounds__(256) void apply_bn(ushort* __restrict__ Y, int ld, const float* __restrict__ st,
                                                const float* __restrict__ gamma, const float* __restrict__ beta,
                                                int relu) {
    __shared__ float sc[512], sh[512];
    int t = threadIdx.x;
    for (int c = t; c < 512; c += 256) {
        float mean = st[c] * (1.f / 65536.f);
        float var = st[512 + c] * (1.f / 65536.f) - mean * mean;
        float rs = rsqrtf(var + 1e-5f);
        float s = rs * gamma[c];
        sc[c] = s; sh[c] = beta[c] - mean * s;
    }
    __syncthreads();
    float s0 = sc[t * 2], s1 = sc[t * 2 + 1], h0 = sh[t * 2], h1v = sh[t * 2 + 1];
    for (int row = blockIdx.x; row < NPIX; row += gridDim.x) {
        uint* p = (uint*)(Y + (size_t)row * ld + t * 2);
        uint v = *p;
        float a = bf2f(v & 0xffffu) * s0 + h0;
        float b = bf2f(v >> 16) * s1 + h1v;
        if (relu) { a = fmaxf(a, 0.f); b = fmaxf(b, 0.f); }
        *p = (uint)f2bf(a) | ((uint)f2bf(b) << 16);
    }
}

// ---------- final: BN (no ReLU) + transpose [n][o] -> (b,o,h,w) fp32 ----------
__global__ __launch_bounds__(256) void finalk(const ushort* __restrict__ y3, const float* __restrict__ st,
                                              const float* __restrict__ gamma, const float* __restrict__ beta,
                                              float* __restrict__ out) {
    __shared__ float tile[32][33];
    int t = threadIdx.x, col = t & 31, rq = t >> 5;
    int n0 = blockIdx.x * 32, o0 = blockIdx.y * 32;
#pragma unroll
    for (int r = 0; r < 4; ++r) {
        int row = rq + r * 8;                        // n_local
        tile[row][col] = bf2f((uint)y3[(size_t)(n0 + row) * 512 + o0 + col]);
    }
    __syncthreads();
    int b = n0 >> 12, s0 = n0 & 4095;
#pragma unroll
    for (int r = 0; r < 4; ++r) {
        int orow = rq + r * 8;                       // o_local
        int o = o0 + orow;
        float mean = st[o] * (1.f / 65536.f);
        float var = st[512 + o] * (1.f / 65536.f) - mean * mean;
        float rs = rsqrtf(var + 1e-5f);
        float sc = rs * gamma[o];
        float sh = beta[o] - mean * sc;
        out[((size_t)b * 512 + o) * 4096 + s0 + col] = tile[col][orow] * sc + sh;
    }
}

// ---------- launch ----------
extern "C" void kernel_launch(void* const* d_in, const int* in_sizes, int n_in,
                              void* d_out, int out_size, void* d_ws, size_t ws_size,
                              hipStream_t stream) {
    (void)in_sizes; (void)n_in; (void)out_size; (void)ws_size;
    const float* x     = (const float*)d_in[0];
    const float* w_in  = (const float*)d_in[1];
    const float* g1    = (const float*)d_in[2];
    const float* b1    = (const float*)d_in[3];
    const float* w_emb = (const float*)d_in[4];
    const float* g2    = (const float*)d_in[5];
    const float* b2    = (const float*)d_in[6];
    const float* w_out = (const float*)d_in[7];
    const float* g3    = (const float*)d_in[8];
    const float* b3    = (const float*)d_in[9];
    float* out = (float*)d_out;

    char* ws = (char*)d_ws;
    // layout (bytes):
    //   [0, 128Mi)           xT [65536][1024] bf16; reused as h2 [65536][512] after GEMM2
    //   [128Mi, 192Mi)       y1 raw [65536][512] bf16; reused as y3
    //   [192Mi, 192Mi+80Mi)  feat [65536][640] bf16 (h1' | gs | zero-weight pad)
    //   then bf16 weights + 3x1024 f32 stats
    ushort* xT   = (ushort*)ws;
    ushort* h2   = (ushort*)ws;
    ushort* y1   = (ushort*)(ws + 134217728);
    ushort* y3   = (ushort*)(ws + 134217728);
    ushort* feat = (ushort*)(ws + 201326592);
    char* wb     = ws + 201326592 + 83886080;
    ushort* wbin  = (ushort*)wb;                             // 512*1024*2 = 1048576
    ushort* wbemb = (ushort*)(wb + 1048576);                 // 512*640*2  = 655360
    ushort* wbout = (ushort*)(wb + 1048576 + 655360);        // 512*512*2  = 524288
    float*  stats = (float*)(wb + 1048576 + 655360 + 524288);// 3*1024 f32

    hipMemsetAsync(stats, 0, 3 * 1024 * sizeof(float), stream);
    convw_all<<<4352, 256, 0, stream>>>(w_in, w_emb, w_out, wbin, wbemb, wbout);
    txpose<<<dim3(128, 32, 16), 256, 0, stream>>>(x, xT);

    // stage 1: conv1x1_in (raw) + fused stats
    gemm256<<<512, 512, 0, stream>>>(xT, wbin, y1, 1024, 512, stats);
    // BN1+ReLU fused into selfcorr staging; writes h1' and gs into feat
    selfcorr2<<<4096, 256, 0, stream>>>(y1, feat, stats, g1, b1);

    // stage 2: embeddingFea + fused stats, then BN+ReLU in place
    gemm256<<<512, 512, 0, stream>>>(feat, wbemb, h2, 640, 512, stats + 1024);
    apply_bn<<<2048, 256, 0, stream>>>(h2, 512, stats + 1024, g2, b2, 1);

    // stage 3: conv1x1_out + fused stats, then BN + transpose to NCHW
    gemm256<<<512, 512, 0, stream>>>(h2, wbout, y3, 512, 512, stats + 2048);
    finalk<<<dim3(2048, 16), 256, 0, stream>>>(y3, stats + 2048, g3, b3, out);
}